// Round 3
// baseline (160.913 us; speedup 1.0000x reference)
//
#include <hip/hip_runtime.h>
#include <math.h>

#define HIDN 128
#define NPTS 32768
#define PTSB 64
#define NBLK (NPTS / PTSB)   // 512 blocks

// Lame: nu=0.49, nu_denom = max(1-0.98,1e-5)=0.02
#define MU_COEF 0.33557046979865773f
#define LM_COEF 16.442953020134228f

typedef float f32x4  __attribute__((ext_vector_type(4)));
typedef short bf16x8 __attribute__((ext_vector_type(8)));

// ws layout:
//   f32[0..3]  loss accumulators (bce, sq, phys, el);  int at f32[7]: block counter
//   f32[16..528)  tab4: 128 x float4 {w0,w1,w2,b1}
//   byte 4096:    BM bf16[9][128 m][128 h]   (294912 B)
// channels: 0 z2(B=W2) | 1..3 t_j(W2*W1j) | 4 wt(W2*kappa) | 5 qtr(W2*s) | 6..8 r_k(W2*W1k*kappa)

__device__ __forceinline__ unsigned short f2bf(float f) {
    unsigned u = __builtin_bit_cast(unsigned, f);
    u += 0x7fffu + ((u >> 16) & 1u);
    return (unsigned short)(u >> 16);
}

__device__ __forceinline__ float tanh_fast(float x) {
    float e = __builtin_amdgcn_exp2f(x * 2.885390081777927f); // e^(2x)
    return 1.0f - 2.0f * __builtin_amdgcn_rcpf(e + 1.0f);
}

__global__ void prep_kernel(const float* __restrict__ W1,
                            const float* __restrict__ b1,
                            const float* __restrict__ W2,
                            const float* __restrict__ Wd,
                            float* __restrict__ ws)
{
    const int idx = blockIdx.x * blockDim.x + threadIdx.x;   // 16384 threads
    const int h = idx & 127;
    const int m = idx >> 7;
    if (idx < 8) ws[idx] = 0.0f;
    const float w0 = W1[0 * HIDN + h];
    const float w1 = W1[1 * HIDN + h];
    const float w2 = W1[2 * HIDN + h];
    if (idx < 128) {
        float4* tab4 = (float4*)(ws + 16);
        tab4[h] = make_float4(w0, w1, w2, b1[h]);
    }
    const float W2v = W2[h * HIDN + m];
    const float kap = w0 * Wd[m * 3 + 0] + w1 * Wd[m * 3 + 1] + w2 * Wd[m * 3 + 2];
    const float s   = w0 * w0 + w1 * w1 + w2 * w2;
    unsigned short* BM = (unsigned short*)((char*)ws + 4096);
    const int o = m * HIDN + h;
    BM[0 * 16384 + o] = f2bf(W2v);
    BM[1 * 16384 + o] = f2bf(W2v * w0);
    BM[2 * 16384 + o] = f2bf(W2v * w1);
    BM[3 * 16384 + o] = f2bf(W2v * w2);
    BM[4 * 16384 + o] = f2bf(W2v * kap);
    BM[5 * 16384 + o] = f2bf(W2v * s);
    BM[6 * 16384 + o] = f2bf(W2v * w0 * kap);
    BM[7 * 16384 + o] = f2bf(W2v * w1 * kap);
    BM[8 * 16384 + o] = f2bf(W2v * w2 * kap);
}

// A-channel index per GEMM channel: {a, g,g,g, g, ag, ag,ag,ag}
__constant__ int AIDX_[9] = {0, 1, 1, 1, 1, 2, 2, 2, 2};

__global__ __launch_bounds__(256, 2) void pinn_main(
    const float* __restrict__ coords,
    const float* __restrict__ labels,
    const float* __restrict__ tstiff,
    const float* __restrict__ b2,
    const float* __restrict__ Wp, const float* __restrict__ bp,
    const float* __restrict__ Wsv, const float* __restrict__ bs,
    const float* __restrict__ Wd,
    const float* __restrict__ ws_ro,
    float* __restrict__ accum,
    float* __restrict__ out)
{
    const float4* tab4 = (const float4*)(ws_ro + 16);
    const unsigned short* BM = (const unsigned short*)((const char*)ws_ro + 4096);

    // LDS: A bf16[3][64 pts][128 h] XOR-swizzled (49152 B) + red f32[4 w][64 b][8] (8192 B)
    __shared__ __align__(16) char smem[57344];
    unsigned short* A  = (unsigned short*)smem;
    float*          red = (float*)(smem + 49152);

    const int t    = threadIdx.x;
    const int w    = __builtin_amdgcn_readfirstlane(t >> 6);
    const int lane = t & 63;
    const int l    = lane & 15;
    const int q    = lane >> 4;
    const int blk  = blockIdx.x;

    // zero red
    {
        float4* r4 = (float4*)red;
        r4[t * 2 + 0] = make_float4(0.f, 0.f, 0.f, 0.f);
        r4[t * 2 + 1] = make_float4(0.f, 0.f, 0.f, 0.f);
    }

    // ---------- phase 1: A channels {a, g, ag} for 64 points ----------
    {
        const int b  = t & 63;
        const int gb = blk * PTSB + b;
        const float x0 = coords[gb * 3 + 0];
        const float x1 = coords[gb * 3 + 1];
        const float x2 = coords[gb * 3 + 2];
#pragma unroll
        for (int i = 0; i < 4; ++i) {
            const int c = w * 4 + i;           // h-chunk of 8 (wave-uniform)
            unsigned pk[3][4];
#pragma unroll
            for (int hh = 0; hh < 8; ++hh) {
                float4 tv = tab4[c * 8 + hh];
                float z  = fmaf(x0, tv.x, fmaf(x1, tv.y, fmaf(x2, tv.z, tv.w)));
                float a  = tanh_fast(z);
                float g  = fmaf(-a, a, 1.0f);
                float ag = a * g;
                unsigned va = f2bf(a), vg = f2bf(g), vag = f2bf(ag);
                if ((hh & 1) == 0) { pk[0][hh >> 1] = va; pk[1][hh >> 1] = vg; pk[2][hh >> 1] = vag; }
                else { pk[0][hh >> 1] |= va << 16; pk[1][hh >> 1] |= vg << 16; pk[2][hh >> 1] |= vag << 16; }
            }
            const int dst = b * 128 + ((c ^ (b & 15)) * 8);
#pragma unroll
            for (int ch = 0; ch < 3; ++ch)
                *(uint4*)(A + ch * 8192 + dst) = make_uint4(pk[ch][0], pk[ch][1], pk[ch][2], pk[ch][3]);
        }
    }
    __syncthreads();

    // ---------- phase 2/3: GEMM passes + epilogue ----------
#pragma unroll
    for (int rt = 0; rt < 2; ++rt) {
        float pv[2][4][8];
#pragma unroll
        for (int a_ = 0; a_ < 2; ++a_)
#pragma unroll
            for (int b_ = 0; b_ < 4; ++b_)
#pragma unroll
                for (int k_ = 0; k_ < 8; ++k_) pv[a_][b_][k_] = 0.f;

#pragma unroll
        for (int mc = 0; mc < 2; ++mc) {
            const int m = mc * 64 + w * 16 + l;
            const float wd0 = Wd[m * 3 + 0];
            const float wd1 = Wd[m * 3 + 1];
            const float wd2 = Wd[m * 3 + 2];
            const float wpv = Wp[m];
            const float wsvv = Wsv[m];
            const float b2v = b2[m];

            f32x4 acc[9][2] = {};
#pragma unroll
            for (int ks = 0; ks < 4; ++ks) {
                bf16x8 af[3][2];
#pragma unroll
                for (int Mt = 0; Mt < 2; ++Mt) {
                    const int br = rt * 32 + Mt * 16 + l;
                    const int sw = ((ks * 4 + q) ^ l) * 8;
#pragma unroll
                    for (int ac = 0; ac < 3; ++ac)
                        af[ac][Mt] = *(const bf16x8*)(A + ac * 8192 + br * 128 + sw);
                }
                bf16x8 bfm[9];
#pragma unroll
                for (int ch = 0; ch < 9; ++ch)
                    bfm[ch] = *(const bf16x8*)(BM + ch * 16384 + m * 128 + ks * 32 + q * 8);
#pragma unroll
                for (int ch = 0; ch < 9; ++ch) {
                    const int ai = (ch == 0) ? 0 : ((ch <= 4) ? 1 : 2);
                    acc[ch][0] = __builtin_amdgcn_mfma_f32_16x16x32_bf16(af[ai][0], bfm[ch], acc[ch][0], 0, 0, 0);
                    acc[ch][1] = __builtin_amdgcn_mfma_f32_16x16x32_bf16(af[ai][1], bfm[ch], acc[ch][1], 0, 0, 0);
                }
            }
            // epilogue: per (b-row, m-lane)
#pragma unroll
            for (int Mt = 0; Mt < 2; ++Mt) {
#pragma unroll
                for (int r = 0; r < 4; ++r) {
                    const float z2 = acc[0][Mt][r] + b2v;
                    const float a2 = tanh_fast(z2);
                    const float g2 = fmaf(-a2, a2, 1.0f);
                    const float d2 = -2.0f * a2 * g2;
                    const float t0 = acc[1][Mt][r], t1 = acc[2][Mt][r], t2 = acc[3][Mt][r];
                    const float wt = acc[4][Mt][r];
                    const float qtr = acc[5][Mt][r];
                    const float r0 = acc[6][Mt][r], r1 = acc[7][Mt][r], r2 = acc[8][Mt][r];
                    const float Lm = fmaf(-2.0f * g2, qtr, d2 * (t0 * t0 + t1 * t1 + t2 * t2));
                    const float m2g2 = -2.0f * g2;
                    const float dwt  = d2 * wt;
                    pv[Mt][r][0] += wpv * a2;
                    pv[Mt][r][1] += wsvv * a2;
                    pv[Mt][r][2] += wd0 * Lm;
                    pv[Mt][r][3] += wd1 * Lm;
                    pv[Mt][r][4] += wd2 * Lm;
                    pv[Mt][r][5] += m2g2 * r0 + dwt * t0;
                    pv[Mt][r][6] += m2g2 * r1 + dwt * t1;
                    pv[Mt][r][7] += m2g2 * r2 + dwt * t2;
                }
            }
        }
        // reduce pv over the 16 m-lanes, add into red
#pragma unroll
        for (int Mt = 0; Mt < 2; ++Mt) {
#pragma unroll
            for (int r = 0; r < 4; ++r) {
                float v[8];
#pragma unroll
                for (int k = 0; k < 8; ++k) {
                    float x = pv[Mt][r][k];
                    x += __shfl_xor(x, 1);
                    x += __shfl_xor(x, 2);
                    x += __shfl_xor(x, 4);
                    x += __shfl_xor(x, 8);
                    v[k] = x;
                }
                if (l == 0) {
                    const int bb = rt * 32 + Mt * 16 + q * 4 + r;
                    float* dst = red + (w * 64 + bb) * 8;
#pragma unroll
                    for (int k = 0; k < 8; ++k) dst[k] += v[k];
                }
            }
        }
    }
    __syncthreads();

    // ---------- phase 4: per-point losses + block reduce + finalize ----------
    if (t < 64) {
        const int b = t;
        float v[8] = {};
#pragma unroll
        for (int ww = 0; ww < 4; ++ww) {
            const float4* src = (const float4*)(red + (ww * 64 + b) * 8);
            float4 p0 = src[0], p1 = src[1];
            v[0] += p0.x; v[1] += p0.y; v[2] += p0.z; v[3] += p0.w;
            v[4] += p1.x; v[5] += p1.y; v[6] += p1.z; v[7] += p1.w;
        }
        const int gb = blk * PTSB + b;
        const float fzp = v[0] + bp[0];
        const float fzs = v[1] + bs[0];
        float pred = 1.0f / (1.0f + expf(-fzp));
        pred = fminf(fmaxf(pred, 1e-7f), 1.0f - 1e-7f);
        const float E = fmaxf(fzs, 0.0f) + log1pf(expf(-fabsf(fzs)));
        const float mu = E * MU_COEF;
        const float cc = E * LM_COEF + mu;
        const float rr0 = mu * v[2] + cc * v[5];
        const float rr1 = mu * v[3] + cc * v[6];
        const float rr2 = mu * v[4] + cc * v[7];
        float phys_t = rr0 * rr0 + rr1 * rr1 + rr2 * rr2;
        float tl = labels[gb];
        tl = fminf(fmaxf(tl, 0.0f), 1.0f);
        float bce_t = -(tl * logf(pred) + (1.0f - tl) * logf(1.0f - pred));
        const float dsv = E - tstiff[gb];
        float sq_t = dsv * dsv;
        float el_t = fmaxf(-E, 0.0f) + fmaxf(E - 15.0f, 0.0f);
#pragma unroll
        for (int off = 1; off < 64; off <<= 1) {
            bce_t  += __shfl_xor(bce_t, off);
            sq_t   += __shfl_xor(sq_t, off);
            phys_t += __shfl_xor(phys_t, off);
            el_t   += __shfl_xor(el_t, off);
        }
        if (t == 0) {
            atomicAdd(accum + 0, bce_t);
            atomicAdd(accum + 1, sq_t);
            atomicAdd(accum + 2, phys_t);
            atomicAdd(accum + 3, el_t);
            __threadfence();
            int old = atomicAdd((int*)(accum + 7), 1);
            if (old == NBLK - 1) {
                const float invB = 1.0f / (float)NPTS;
                const float bce  = atomicAdd(accum + 0, 0.0f) * invB;
                const float data = bce + 0.5f * atomicAdd(accum + 1, 0.0f) * invB;
                const float phys = atomicAdd(accum + 2, 0.0f) * invB;
                const float el   = atomicAdd(accum + 3, 0.0f) * invB;
                out[0] = data + 0.1f * phys + 0.05f * el;
                out[1] = data;
                out[2] = phys;
                out[3] = el;
            }
        }
    }
}

extern "C" void kernel_launch(void* const* d_in, const int* in_sizes, int n_in,
                              void* d_out, int out_size, void* d_ws, size_t ws_size,
                              hipStream_t stream)
{
    const float* coords = (const float*)d_in[0];
    const float* labels = (const float*)d_in[1];
    const float* tstiff = (const float*)d_in[2];
    const float* W1  = (const float*)d_in[3];
    const float* b1  = (const float*)d_in[4];
    const float* W2  = (const float*)d_in[5];
    const float* b2  = (const float*)d_in[6];
    const float* Wp  = (const float*)d_in[7];
    const float* bp  = (const float*)d_in[8];
    const float* Wsv = (const float*)d_in[9];
    const float* bs  = (const float*)d_in[10];
    const float* Wd  = (const float*)d_in[11];
    // d_in[12] = bd : unused (constant offset has zero Hessian)

    float* ws  = (float*)d_ws;
    float* out = (float*)d_out;

    prep_kernel<<<64, 256, 0, stream>>>(W1, b1, W2, Wd, ws);
    pinn_main<<<NBLK, 256, 0, stream>>>(coords, labels, tstiff, b2,
                                        Wp, bp, Wsv, bs, Wd, ws, ws, out);
}

// Round 4
// 146.627 us; speedup vs baseline: 1.0974x; 1.0974x over previous
//
#include <hip/hip_runtime.h>
#include <math.h>

#define HIDN 128
#define NPTS 32768
#define PTSB 64
#define NBLK (NPTS / PTSB)   // 512 blocks

// Lame: nu=0.49, nu_denom = max(1-0.98,1e-5)=0.02
#define MU_COEF 0.33557046979865773f
#define LM_COEF 16.442953020134228f

typedef float f32x4  __attribute__((ext_vector_type(4)));
typedef short bf16x8 __attribute__((ext_vector_type(8)));

// ws layout:
//   f32[0..3]  loss accumulators (bce, sq, phys, el);  int at f32[7]: block counter
//   f32[16..528)  tab4: 128 x float4 {w0,w1,w2,b1}
//   byte 4096:    BM bf16[9][128 m][128 h]   (294912 B)
// channels: 0 z2(W2) | 1..3 t_j(W2*W1j) | 4 wt(W2*kappa) | 5 qtr2(-2*W2*s) | 6..8 r2_k(-2*W2*W1k*kappa)

__device__ __forceinline__ unsigned short f2bf(float f) {
    unsigned u = __builtin_bit_cast(unsigned, f);
    u += 0x7fffu + ((u >> 16) & 1u);
    return (unsigned short)(u >> 16);
}

__device__ __forceinline__ float tanh_fast(float x) {
    float e = __builtin_amdgcn_exp2f(x * 2.885390081777927f); // e^(2x)
    return 1.0f - 2.0f * __builtin_amdgcn_rcpf(e + 1.0f);
}

__global__ void prep_kernel(const float* __restrict__ W1,
                            const float* __restrict__ b1,
                            const float* __restrict__ W2,
                            const float* __restrict__ Wd,
                            float* __restrict__ ws)
{
    const int idx = blockIdx.x * blockDim.x + threadIdx.x;   // 16384 threads
    const int h = idx & 127;
    const int m = idx >> 7;
    if (idx < 8) ws[idx] = 0.0f;
    const float w0 = W1[0 * HIDN + h];
    const float w1 = W1[1 * HIDN + h];
    const float w2 = W1[2 * HIDN + h];
    if (idx < 128) {
        float4* tab4 = (float4*)(ws + 16);
        tab4[h] = make_float4(w0, w1, w2, b1[h]);
    }
    const float W2v = W2[h * HIDN + m];
    const float kap = w0 * Wd[m * 3 + 0] + w1 * Wd[m * 3 + 1] + w2 * Wd[m * 3 + 2];
    const float s   = w0 * w0 + w1 * w1 + w2 * w2;
    unsigned short* BM = (unsigned short*)((char*)ws + 4096);
    const int o = m * HIDN + h;
    BM[0 * 16384 + o] = f2bf(W2v);
    BM[1 * 16384 + o] = f2bf(W2v * w0);
    BM[2 * 16384 + o] = f2bf(W2v * w1);
    BM[3 * 16384 + o] = f2bf(W2v * w2);
    BM[4 * 16384 + o] = f2bf(W2v * kap);
    BM[5 * 16384 + o] = f2bf(-2.0f * W2v * s);
    BM[6 * 16384 + o] = f2bf(-2.0f * W2v * w0 * kap);
    BM[7 * 16384 + o] = f2bf(-2.0f * W2v * w1 * kap);
    BM[8 * 16384 + o] = f2bf(-2.0f * W2v * w2 * kap);
}

__global__ __launch_bounds__(256, 2) void pinn_main(
    const float* __restrict__ coords,
    const float* __restrict__ labels,
    const float* __restrict__ tstiff,
    const float* __restrict__ b2,
    const float* __restrict__ Wp, const float* __restrict__ bp,
    const float* __restrict__ Wsv, const float* __restrict__ bs,
    const float* __restrict__ Wd,
    const float* __restrict__ ws_ro,
    float* __restrict__ accum,
    float* __restrict__ out)
{
    const float4* tab4 = (const float4*)(ws_ro + 16);
    const unsigned short* BM = (const unsigned short*)((const char*)ws_ro + 4096);

    // LDS: A bf16[3][64 pts][128 h] XOR-swizzled (49152 B) + red f32[4 w][64 pt][8] (8192 B)
    __shared__ __align__(16) char smem[57344];
    unsigned short* A   = (unsigned short*)smem;
    float*          red = (float*)(smem + 49152);

    const int t    = threadIdx.x;
    const int w    = __builtin_amdgcn_readfirstlane(t >> 6);
    const int lane = t & 63;
    const int l    = lane & 15;
    const int q    = lane >> 4;
    const int blk  = blockIdx.x;

    // zero red
    {
        float4* r4 = (float4*)red;
        r4[t * 2 + 0] = make_float4(0.f, 0.f, 0.f, 0.f);
        r4[t * 2 + 1] = make_float4(0.f, 0.f, 0.f, 0.f);
    }

    // ---------- phase 1: point channels {a, g, ag} for 64 points ----------
    {
        const int b  = t & 63;
        const int gb = blk * PTSB + b;
        const float x0 = coords[gb * 3 + 0];
        const float x1 = coords[gb * 3 + 1];
        const float x2 = coords[gb * 3 + 2];
#pragma unroll
        for (int i = 0; i < 4; ++i) {
            const int c = w * 4 + i;           // h-chunk of 8 (wave-uniform)
            unsigned pk[3][4];
#pragma unroll
            for (int hh = 0; hh < 8; ++hh) {
                float4 tv = tab4[c * 8 + hh];
                float z  = fmaf(x0, tv.x, fmaf(x1, tv.y, fmaf(x2, tv.z, tv.w)));
                float a  = tanh_fast(z);
                float g  = fmaf(-a, a, 1.0f);
                float ag = a * g;
                unsigned va = f2bf(a), vg = f2bf(g), vag = f2bf(ag);
                if ((hh & 1) == 0) { pk[0][hh >> 1] = va; pk[1][hh >> 1] = vg; pk[2][hh >> 1] = vag; }
                else { pk[0][hh >> 1] |= va << 16; pk[1][hh >> 1] |= vg << 16; pk[2][hh >> 1] |= vag << 16; }
            }
            const int dst = b * 128 + ((c ^ (b & 15)) * 8);
#pragma unroll
            for (int ch = 0; ch < 3; ++ch)
                *(uint4*)(A + ch * 8192 + dst) = make_uint4(pk[ch][0], pk[ch][1], pk[ch][2], pk[ch][3]);
        }
    }
    __syncthreads();

    // ---------- phase 2: GEMM (A = BM rows of m, B = point channels) ----------
#pragma unroll
    for (int mc = 0; mc < 2; ++mc) {
        const int mrow = mc * 64 + w * 16;       // this wave's m-tile base
        // per-row m scalars (row = q*4 + r)
        float b2v[4], wpv[4], wsvv[4], wd0v[4], wd1v[4], wd2v[4];
#pragma unroll
        for (int r = 0; r < 4; ++r) {
            const int m = mrow + q * 4 + r;
            b2v[r]  = b2[m];
            wpv[r]  = Wp[m];
            wsvv[r] = Wsv[m];
            wd0v[r] = Wd[m * 3 + 0];
            wd1v[r] = Wd[m * 3 + 1];
            wd2v[r] = Wd[m * 3 + 2];
        }
        const unsigned short* bmrow = BM + (mrow + l) * HIDN;  // lane's A-row (m = mrow + l)

#pragma unroll
        for (int pp = 0; pp < 2; ++pp) {          // 2 column-tile pairs (32 pts each)
            f32x4 acc[9][2] = {};
#pragma unroll
            for (int ks = 0; ks < 4; ++ks) {
                bf16x8 pf[3][2];
#pragma unroll
                for (int Nt = 0; Nt < 2; ++Nt) {
                    const int pt = pp * 32 + Nt * 16 + l;
                    const int sw = ((ks * 4 + q) ^ l) * 8;
#pragma unroll
                    for (int c = 0; c < 3; ++c)
                        pf[c][Nt] = *(const bf16x8*)(A + c * 8192 + pt * 128 + sw);
                }
                const int ho = ks * 32 + q * 8;
                bf16x8 am[9];
#pragma unroll
                for (int ch = 0; ch < 9; ++ch)
                    am[ch] = *(const bf16x8*)(bmrow + ch * 16384 + ho);
#pragma unroll
                for (int ch = 0; ch < 9; ++ch) {
                    const int ci = (ch == 0) ? 0 : ((ch <= 4) ? 1 : 2);
                    acc[ch][0] = __builtin_amdgcn_mfma_f32_16x16x32_bf16(am[ch], pf[ci][0], acc[ch][0], 0, 0, 0);
                    acc[ch][1] = __builtin_amdgcn_mfma_f32_16x16x32_bf16(am[ch], pf[ci][1], acc[ch][1], 0, 0, 0);
                }
            }
            // ---------- epilogue: row m = mrow + q*4 + r, col pt = pp*32 + Nt*16 + l ----------
#pragma unroll
            for (int Nt = 0; Nt < 2; ++Nt) {
                float s0 = 0.f, s1 = 0.f, s2 = 0.f, s3 = 0.f;
                float s4 = 0.f, s5 = 0.f, s6 = 0.f, s7 = 0.f;
#pragma unroll
                for (int r = 0; r < 4; ++r) {
                    const float z2 = acc[0][Nt][r] + b2v[r];
                    const float a2 = tanh_fast(z2);
                    const float g2 = fmaf(-a2, a2, 1.0f);
                    const float na2 = -2.0f * a2;
                    const float d2 = na2 * g2;
                    const float t0 = acc[1][Nt][r], t1 = acc[2][Nt][r], t2 = acc[3][Nt][r];
                    const float wt = acc[4][Nt][r];
                    const float qtr2 = acc[5][Nt][r];   // -2*qtr baked
                    const float r20 = acc[6][Nt][r], r21 = acc[7][Nt][r], r22 = acc[8][Nt][r];
                    const float tt = fmaf(t2, t2, fmaf(t1, t1, t0 * t0));
                    const float Lm = fmaf(g2, qtr2, d2 * tt);
                    const float dwt = d2 * wt;
                    s0 = fmaf(wpv[r], a2, s0);
                    s1 = fmaf(wsvv[r], a2, s1);
                    s2 = fmaf(wd0v[r], Lm, s2);
                    s3 = fmaf(wd1v[r], Lm, s3);
                    s4 = fmaf(wd2v[r], Lm, s4);
                    s5 = fmaf(g2, r20, fmaf(dwt, t0, s5));
                    s6 = fmaf(g2, r21, fmaf(dwt, t1, s6));
                    s7 = fmaf(g2, r22, fmaf(dwt, t2, s7));
                }
                // reduce over the 4 quads (rows) -> full sum over this m-tile
                s0 += __shfl_xor(s0, 16); s0 += __shfl_xor(s0, 32);
                s1 += __shfl_xor(s1, 16); s1 += __shfl_xor(s1, 32);
                s2 += __shfl_xor(s2, 16); s2 += __shfl_xor(s2, 32);
                s3 += __shfl_xor(s3, 16); s3 += __shfl_xor(s3, 32);
                s4 += __shfl_xor(s4, 16); s4 += __shfl_xor(s4, 32);
                s5 += __shfl_xor(s5, 16); s5 += __shfl_xor(s5, 32);
                s6 += __shfl_xor(s6, 16); s6 += __shfl_xor(s6, 32);
                s7 += __shfl_xor(s7, 16); s7 += __shfl_xor(s7, 32);
                if (q == 0) {
                    float* dst = red + (w * 64 + pp * 32 + Nt * 16 + l) * 8;
                    float4* d4 = (float4*)dst;
                    float4 o0 = d4[0], o1 = d4[1];
                    d4[0] = make_float4(o0.x + s0, o0.y + s1, o0.z + s2, o0.w + s3);
                    d4[1] = make_float4(o1.x + s4, o1.y + s5, o1.z + s6, o1.w + s7);
                }
            }
        }
    }
    __syncthreads();

    // ---------- phase 4: per-point losses + block reduce + finalize ----------
    if (t < 64) {
        const int b = t;
        float v[8] = {};
#pragma unroll
        for (int ww = 0; ww < 4; ++ww) {
            const float4* src = (const float4*)(red + (ww * 64 + b) * 8);
            float4 p0 = src[0], p1 = src[1];
            v[0] += p0.x; v[1] += p0.y; v[2] += p0.z; v[3] += p0.w;
            v[4] += p1.x; v[5] += p1.y; v[6] += p1.z; v[7] += p1.w;
        }
        const int gb = blk * PTSB + b;
        const float fzp = v[0] + bp[0];
        const float fzs = v[1] + bs[0];
        float pred = 1.0f / (1.0f + expf(-fzp));
        pred = fminf(fmaxf(pred, 1e-7f), 1.0f - 1e-7f);
        const float E = fmaxf(fzs, 0.0f) + log1pf(expf(-fabsf(fzs)));
        const float mu = E * MU_COEF;
        const float cc = E * LM_COEF + mu;
        const float rr0 = mu * v[2] + cc * v[5];
        const float rr1 = mu * v[3] + cc * v[6];
        const float rr2 = mu * v[4] + cc * v[7];
        float phys_t = rr0 * rr0 + rr1 * rr1 + rr2 * rr2;
        float tl = labels[gb];
        tl = fminf(fmaxf(tl, 0.0f), 1.0f);
        float bce_t = -(tl * logf(pred) + (1.0f - tl) * logf(1.0f - pred));
        const float dsv = E - tstiff[gb];
        float sq_t = dsv * dsv;
        float el_t = fmaxf(-E, 0.0f) + fmaxf(E - 15.0f, 0.0f);
#pragma unroll
        for (int off = 1; off < 64; off <<= 1) {
            bce_t  += __shfl_xor(bce_t, off);
            sq_t   += __shfl_xor(sq_t, off);
            phys_t += __shfl_xor(phys_t, off);
            el_t   += __shfl_xor(el_t, off);
        }
        if (t == 0) {
            atomicAdd(accum + 0, bce_t);
            atomicAdd(accum + 1, sq_t);
            atomicAdd(accum + 2, phys_t);
            atomicAdd(accum + 3, el_t);
            __threadfence();
            int old = atomicAdd((int*)(accum + 7), 1);
            if (old == NBLK - 1) {
                const float invB = 1.0f / (float)NPTS;
                const float bce  = atomicAdd(accum + 0, 0.0f) * invB;
                const float data = bce + 0.5f * atomicAdd(accum + 1, 0.0f) * invB;
                const float phys = atomicAdd(accum + 2, 0.0f) * invB;
                const float el   = atomicAdd(accum + 3, 0.0f) * invB;
                out[0] = data + 0.1f * phys + 0.05f * el;
                out[1] = data;
                out[2] = phys;
                out[3] = el;
            }
        }
    }
}

extern "C" void kernel_launch(void* const* d_in, const int* in_sizes, int n_in,
                              void* d_out, int out_size, void* d_ws, size_t ws_size,
                              hipStream_t stream)
{
    const float* coords = (const float*)d_in[0];
    const float* labels = (const float*)d_in[1];
    const float* tstiff = (const float*)d_in[2];
    const float* W1  = (const float*)d_in[3];
    const float* b1  = (const float*)d_in[4];
    const float* W2  = (const float*)d_in[5];
    const float* b2  = (const float*)d_in[6];
    const float* Wp  = (const float*)d_in[7];
    const float* bp  = (const float*)d_in[8];
    const float* Wsv = (const float*)d_in[9];
    const float* bs  = (const float*)d_in[10];
    const float* Wd  = (const float*)d_in[11];
    // d_in[12] = bd : unused (constant offset has zero Hessian)

    float* ws  = (float*)d_ws;
    float* out = (float*)d_out;

    prep_kernel<<<64, 256, 0, stream>>>(W1, b1, W2, Wd, ws);
    pinn_main<<<NBLK, 256, 0, stream>>>(coords, labels, tstiff, b2,
                                        Wp, bp, Wsv, bs, Wd, ws, ws, out);
}